// Round 6
// baseline (1600.003 us; speedup 1.0000x reference)
//
#include <hip/hip_runtime.h>
#include <hip/hip_bf16.h>
#include <cstddef>
#include <cstdint>

typedef unsigned short u16;

#define Mtok  16384
#define Ncode 8192
#define Kdim  256
#define NSPLIT 8
#define NPER  (Ncode / NSPLIT)    // 1024 codes per split
#define NT    (NPER / 128)        // 8 column tiles of 128 per block
#define TH_MARGIN 1.5f            // single-product bf16 err std ~0.1 -> >10 sigma
#define RCHUNK 256                // rescue: codes per chunk
#define RNCH  (Ncode / RCHUNK)    // 32 chunks

typedef __bf16 bf16x8 __attribute__((ext_vector_type(8)));
typedef float  f32x4  __attribute__((ext_vector_type(4)));

#define LDSP(p) ((__attribute__((address_space(3))) void*)(p))
#define GPTR(p) ((const __attribute__((address_space(1))) void*)(p))

__device__ __forceinline__ u16 f2bf(float x) {
    __hip_bfloat16 h = __float2bfloat16(x);
    return *reinterpret_cast<u16*>(&h);
}

// ---------------------------------------------------------------------------
// Kernel 1: transpose z -> z_out (fp32), plus bf16 s = -2*z (hi only now:
// the lo-term correction was replaced by the wider rescue margin).
// Also zeroes the rescue counter (stream-ordered before k_merge).
__global__ __launch_bounds__(256) void k_prep(const float* __restrict__ z,
        float* __restrict__ z_out, u16* __restrict__ sh, int* __restrict__ count) {
    __shared__ float tile[32][33];
    const int b  = blockIdx.z;
    const int c0 = blockIdx.y * 32;
    const int p0 = blockIdx.x * 32;
    const int tx = threadIdx.x;   // 0..31
    const int ty = threadIdx.y;   // 0..7
    if (b == 0 && c0 == 0 && p0 == 0 && tx == 0 && ty == 0) count[0] = 0;
    const float* src = z + ((size_t)b * Kdim + c0) * 1024 + p0;
#pragma unroll
    for (int i = 0; i < 32; i += 8)
        tile[ty + i][tx] = src[(size_t)(ty + i) * 1024 + tx];
    __syncthreads();
#pragma unroll
    for (int i = 0; i < 32; i += 8) {
        const float v = tile[tx][ty + i];
        const size_t m = (size_t)b * 1024 + p0 + ty + i;
        const int    c = c0 + tx;
        z_out[m * Kdim + c] = v;
        sh[m * Kdim + c] = f2bf(-2.0f * v);
    }
}

// ---------------------------------------------------------------------------
// Kernel 2: per-code ||w||^2 plus bf16 wh. One wave per code row.
__global__ __launch_bounds__(64) void k_wsplit(const float* __restrict__ w,
        float* __restrict__ wnorm, u16* __restrict__ wh) {
    const int row  = blockIdx.x;
    const int lane = threadIdx.x;
    const float4 v = ((const float4*)(w + (size_t)row * Kdim))[lane];
    float s = v.x * v.x + v.y * v.y + v.z * v.z + v.w * v.w;
#pragma unroll
    for (int off = 32; off > 0; off >>= 1)
        s += __shfl_down(s, off, 64);
    if (lane == 0) wnorm[row] = s;
    ushort4 ph;
    u16* hp = (u16*)&ph;
    hp[0] = f2bf(v.x); hp[1] = f2bf(v.y); hp[2] = f2bf(v.z); hp[3] = f2bf(v.w);
    *(ushort4*)(wh + (size_t)row * Kdim + lane * 4) = ph;
}

// ---------------------------------------------------------------------------
// Kernel 3 (round-9): SINGLE-PRODUCT d ~= wnorm + sh*wh on the round-2-proven
// skeleton (two barriers/round, double-buffered B, stage-at-END, counted
// vmcnt). The 3-product hi/lo scheme was 130-sigma over-provisioned; the
// exact-fp32 rescue makes TH a perf knob, so margin 0.02 -> 1.5 buys a 3x
// MFMA reduction + 2x staging reduction. A-frags now 64 VGPRs (was 128) --
// strictly LESS register pressure than the schedule the allocator already
// fit (rounds 3-5's restructures all spilled the A-array wholesale: the
// 135-165 MB WRITE_SIZE signature; this reverts to the proven skeleton).
// Round rr: vmcnt(2) [stage(rr) landed, stage(rr+1) in flight] -> s_barrier
//   -> [ks==0: acc=wn] -> 8x{ds_read bh + 2 MFMA} (setprio) -> lgkmcnt(0)
//   -> s_barrier -> stage(rr+2 -> buf[rr&1], 2 loads). Round 63: vmcnt(0).
__global__ __launch_bounds__(256, 2) void k_mfma(
        const u16* __restrict__ sh, const u16* __restrict__ wh,
        const float* __restrict__ wnorm,
        float* __restrict__ pv1, int* __restrict__ pi1, float* __restrict__ pv2) {
    __shared__ __align__(16) u16 Bh[2][128 * 32];
    __shared__ __align__(16) float wn_lds[NPER];
    const int tid  = threadIdx.x;
    const int w    = tid >> 6;          // wave 0..3
    const int lane = tid & 63;
    const int l15  = lane & 15;
    const int q    = lane >> 4;         // 0..3
    const int y    = blockIdx.x & 7;    // n-split (XCD pin)
    const int x    = blockIdx.x >> 3;   // m-tile
    const int m0   = x * 128;
    const int n0   = y * NPER;
    const int srow = lane >> 2;         // staging: 16 rows x 4 16B-chunks
    const int sq   = lane & 3;
    const int sqg  = sq ^ ((srow >> 1) & 3);     // pre-swizzled source chunk
    const int qsw  = (q ^ ((l15 >> 1) & 3)) * 8; // swizzled read slot (elems)

    // ---- prologue: A fragments -> registers (direct global, un-swizzled) ---
    bf16x8 ah[8][2];
#pragma unroll
    for (int ks = 0; ks < 8; ++ks)
#pragma unroll
        for (int i = 0; i < 2; ++i) {
            const size_t ra = (size_t)(m0 + w * 32 + i * 16 + l15) * Kdim
                              + ks * 32 + q * 8;
            ah[ks][i] = *(const bf16x8*)(sh + ra);
        }
    // wnorm -> LDS: each lane 16B, wave-uniform LDS base (gload_lds rule)
    __builtin_amdgcn_global_load_lds(GPTR(wnorm + n0 + w * 256 + lane * 4),
                                     LDSP(wn_lds + w * 256), 16, 0, 0);
    // stage B for rounds 0 and 1 (2 loads/wave each)
#pragma unroll
    for (int rr = 0; rr < 2; ++rr) {
        const int kk = rr * 32;
#pragma unroll
        for (int t = 0; t < 2; ++t) {
            const int r  = w * 32 + t * 16 + srow;
            const int lb = (w * 32 + t * 16) * 32;
            const size_t gb = (size_t)(n0 + r) * Kdim + kk + sqg * 8;
            __builtin_amdgcn_global_load_lds(GPTR(wh + gb), LDSP(&Bh[rr][lb]), 16, 0, 0);
        }
    }

    float v1[8], v2[8]; int i1[8];      // slot s=i*4+r -> row m0+w*32+i*16+q*4+r
#pragma unroll
    for (int s = 0; s < 8; ++s) { v1[s] = 3.0e38f; v2[s] = 3.0e38f; i1[s] = 0x7fffffff; }

    f32x4 acc[2][8];
#pragma unroll 1
    for (int nt = 0; nt < NT; ++nt) {
        const int nb = n0 + nt * 128;
#pragma unroll
        for (int ks = 0; ks < 8; ++ks) {
            const int rr  = nt * 8 + ks;
            const int par = rr & 1;
            // vmcnt ledger: outstanding = stage(rr)[2] + stage(rr+1)[2];
            // round 0 additionally A(16)+wn(1) older (needed now anyway);
            // round 63 has only stage(63)[2] -> must drain to 0.
            if (rr == NT * 8 - 1) {
                asm volatile("s_waitcnt vmcnt(0)" ::: "memory");
            } else {
                asm volatile("s_waitcnt vmcnt(2)" ::: "memory");
            }
            __builtin_amdgcn_s_barrier();   // all waves' stages for rr visible
            if (ks == 0) {
#pragma unroll
                for (int j = 0; j < 8; ++j) {
                    const float wv = wn_lds[nt * 128 + j * 16 + l15];
#pragma unroll
                    for (int i = 0; i < 2; ++i) {
                        acc[i][j][0] = wv; acc[i][j][1] = wv;
                        acc[i][j][2] = wv; acc[i][j][3] = wv;
                    }
                }
            }
            __builtin_amdgcn_s_setprio(1);
#pragma unroll
            for (int j = 0; j < 8; ++j) {
                const bf16x8 bh_ = *(const bf16x8*)&Bh[par][(j * 16 + l15) * 32 + qsw];
                acc[0][j] = __builtin_amdgcn_mfma_f32_16x16x32_bf16(ah[ks][0], bh_, acc[0][j], 0, 0, 0);
                acc[1][j] = __builtin_amdgcn_mfma_f32_16x16x32_bf16(ah[ks][1], bh_, acc[1][j], 0, 0, 0);
            }
            __builtin_amdgcn_s_setprio(0);
            // all my ds_reads of buf[par] done (stage below can't overtake)
            asm volatile("s_waitcnt lgkmcnt(0)" ::: "memory");
            __builtin_amdgcn_s_barrier();   // all waves done reading buf[par]
            if (rr + 2 < NT * 8) {          // stage round rr+2 into buf[par]
                const int rr2 = rr + 2;
                const int nb2 = n0 + (rr2 >> 3) * 128;
                const int kk2 = (rr2 & 7) * 32;
#pragma unroll
                for (int t = 0; t < 2; ++t) {
                    const int r  = w * 32 + t * 16 + srow;
                    const int lb = (w * 32 + t * 16) * 32;
                    const size_t gb = (size_t)(nb2 + r) * Kdim + kk2 + sqg * 8;
                    __builtin_amdgcn_global_load_lds(GPTR(wh + gb), LDSP(&Bh[par][lb]), 16, 0, 0);
                }
            }
        }
        // top-2 update (idx ascending per lane scan -> strict < = first-min)
#pragma unroll
        for (int i = 0; i < 2; ++i)
#pragma unroll
            for (int r = 0; r < 4; ++r) {
                const int s = i * 4 + r;
#pragma unroll
                for (int j = 0; j < 8; ++j) {
                    const float d   = acc[i][j][r];
                    const int   idx = nb + j * 16 + l15;
                    const bool  bt  = d < v1[s];
                    const float lose = bt ? v1[s] : d;
                    v2[s] = fminf(v2[s], lose);
                    v1[s] = bt ? d : v1[s];
                    i1[s] = bt ? idx : i1[s];
                }
            }
    }
    // butterfly merge across the 16 lanes sharing each row (lex on idx)
#pragma unroll
    for (int msk = 1; msk < 16; msk <<= 1) {
#pragma unroll
        for (int s = 0; s < 8; ++s) {
            const float ov1 = __shfl_xor(v1[s], msk, 64);
            const int   oi1 = __shfl_xor(i1[s], msk, 64);
            const float ov2 = __shfl_xor(v2[s], msk, 64);
            const bool  keep = (v1[s] < ov1) || (v1[s] == ov1 && i1[s] < oi1);
            const float lose = keep ? ov1 : v1[s];
            v1[s] = keep ? v1[s] : ov1;
            i1[s] = keep ? i1[s] : oi1;
            v2[s] = fminf(fminf(v2[s], ov2), lose);
        }
    }
    if (l15 == 0) {
#pragma unroll
        for (int i = 0; i < 2; ++i)
#pragma unroll
            for (int r = 0; r < 4; ++r) {
                const int s = i * 4 + r;
                const int m = m0 + w * 32 + i * 16 + q * 4 + r;
                pv1[(size_t)y * Mtok + m] = v1[s];
                pi1[(size_t)y * Mtok + m] = i1[s];
                pv2[(size_t)y * Mtok + m] = v2[s];
            }
    }
}

// ---------------------------------------------------------------------------
// Kernel 4: merge 8 split partials -> provisional idx + flag + compacted list.
__global__ __launch_bounds__(256) void k_merge(
        const float* __restrict__ pv1, const int* __restrict__ pi1,
        const float* __restrict__ pv2, int* __restrict__ fidx,
        int* __restrict__ flag, int* __restrict__ list, int* __restrict__ count) {
    const int t = blockIdx.x * 256 + threadIdx.x;
    float b1 = 3.0e38f, b2 = 3.0e38f; int bi = 0x7fffffff;
#pragma unroll
    for (int s = 0; s < NSPLIT; ++s) {
        const float v1 = pv1[(size_t)s * Mtok + t];
        const int   i1 = pi1[(size_t)s * Mtok + t];
        const float v2 = pv2[(size_t)s * Mtok + t];
        const bool  wn = (v1 < b1) || (v1 == b1 && i1 < bi);
        const float lose = wn ? b1 : v1;
        b2 = fminf(fminf(b2, v2), lose);
        b1 = wn ? v1 : b1;
        bi = wn ? i1 : bi;
    }
    fidx[t] = bi;
    const int f = (b2 - b1 < TH_MARGIN) ? 1 : 0;
    flag[t] = f;
    if (f) { const int p = atomicAdd(count, 1); list[p] = t; }
}

// ---------------------------------------------------------------------------
// Kernel 5: exact fp32 rescore, parallelized over code chunks.
// grid (RNCH, 64): block = (chunk bx, one listed token per y-iteration).
// Each wave handles codes n = bx*256 + 4*i + wv (ascending), whole-row
// coalesced 1 KB reads, 64-lane butterfly dot-reduce. Cross-wave lex merge
// -> one (val,idx) partial per (token, chunk).
__global__ __launch_bounds__(256) void k_rescue(
        const float* __restrict__ z_out, const float* __restrict__ w,
        const float* __restrict__ wnorm, const int* __restrict__ list,
        const int* __restrict__ count,
        float* __restrict__ pcv, int* __restrict__ pci) {
    const int bx   = blockIdx.x;       // chunk
    const int tid  = threadIdx.x;
    const int wv   = tid >> 6;
    const int lane = tid & 63;
    __shared__ float rv[4];
    __shared__ int   ri[4];
    const int cnt = count[0];
    for (int it = blockIdx.y; it < cnt; it += gridDim.y) {
        const int t = list[it];
        const float4 zv = *(const float4*)(z_out + (size_t)t * Kdim + lane * 4);
        float bd = 3.0e38f; int bn = 0x7fffffff;
#pragma unroll 4
        for (int i = 0; i < RCHUNK / 4; ++i) {
            const int n = bx * RCHUNK + i * 4 + wv;
            const float4 wr = *(const float4*)(w + (size_t)n * Kdim + lane * 4);
            float s = fmaf(wr.x, zv.x, fmaf(wr.y, zv.y,
                      fmaf(wr.z, zv.z, wr.w * zv.w)));
#pragma unroll
            for (int msk = 1; msk < 64; msk <<= 1)
                s += __shfl_xor(s, msk, 64);
            const float d = wnorm[n] - 2.0f * s;
            if (d < bd) { bd = d; bn = n; }
        }
        if (lane == 0) { rv[wv] = bd; ri[wv] = bn; }
        __syncthreads();
        if (tid == 0) {
            float b = rv[0]; int bi = ri[0];
#pragma unroll
            for (int k = 1; k < 4; ++k)
                if (rv[k] < b || (rv[k] == b && ri[k] < bi)) { b = rv[k]; bi = ri[k]; }
            pcv[(size_t)t * RNCH + bx] = b;
            pci[(size_t)t * RNCH + bx] = bi;
        }
        __syncthreads();
    }
}

// ---------------------------------------------------------------------------
// Kernel 6: gather z_q = weight[idx], write float indices. One wave/token.
// For flagged tokens, merge the RNCH rescue partials in-wave first.
__global__ __launch_bounds__(256) void k_gather(
        const float* __restrict__ w, const int* __restrict__ fidx,
        const int* __restrict__ flag,
        const float* __restrict__ pcv, const int* __restrict__ pci,
        float* __restrict__ zq, float* __restrict__ idx_out) {
    const int token = blockIdx.x * 4 + (threadIdx.x >> 6);
    const int lane  = threadIdx.x & 63;
    int bi = fidx[token];
    if (flag[token]) {
        float v = 3.0e38f; int ii = 0x7fffffff;
        if (lane < RNCH) {
            v  = pcv[(size_t)token * RNCH + lane];
            ii = pci[(size_t)token * RNCH + lane];
        }
#pragma unroll
        for (int msk = 1; msk < 64; msk <<= 1) {
            const float ov = __shfl_xor(v, msk, 64);
            const int   oi = __shfl_xor(ii, msk, 64);
            if (ov < v || (ov == v && oi < ii)) { v = ov; ii = oi; }
        }
        bi = ii;   // uniform across lanes after full butterfly
    }
    const float4 u = *(const float4*)(w + (size_t)bi * Kdim + lane * 4);
    *(float4*)(zq + (size_t)token * Kdim + lane * 4) = u;
    if (lane == 0) idx_out[token] = (float)bi;
}

// ---------------------------------------------------------------------------
extern "C" void kernel_launch(void* const* d_in, const int* in_sizes, int n_in,
                              void* d_out, int out_size, void* d_ws, size_t ws_size,
                              hipStream_t stream) {
    const float* z = (const float*)d_in[0];
    const float* w = (const float*)d_in[1];

    float* z_out  = (float*)d_out;                          // [16384, 256]
    float* zq     = z_out + (size_t)Mtok * Kdim;            // [16384, 256]
    float* idxout = zq + (size_t)Mtok * Kdim;               // [16384]

    char* ws = (char*)d_ws;
    u16*   sh    = (u16*)ws;                       ws += (size_t)Mtok * Kdim * 2;
    u16*   wh    = (u16*)ws;                       ws += (size_t)Ncode * Kdim * 2;
    float* wnorm = (float*)ws;                     ws += (size_t)Ncode * 4;
    float* pv1   = (float*)ws;                     ws += (size_t)NSPLIT * Mtok * 4;
    int*   pi1   = (int*)ws;                       ws += (size_t)NSPLIT * Mtok * 4;
    float* pv2   = (float*)ws;                     ws += (size_t)NSPLIT * Mtok * 4;
    int*   fidx  = (int*)ws;                       ws += (size_t)Mtok * 4;
    int*   flag  = (int*)ws;                       ws += (size_t)Mtok * 4;
    int*   list  = (int*)ws;                       ws += (size_t)Mtok * 4;
    int*   count = (int*)ws;                       ws += 256;
    float* pcv   = (float*)ws;                     ws += (size_t)Mtok * RNCH * 4;
    int*   pci   = (int*)ws;                       ws += (size_t)Mtok * RNCH * 4;

    k_prep<<<dim3(1024 / 32, Kdim / 32, 16), dim3(32, 8), 0, stream>>>(z, z_out, sh, count);
    k_wsplit<<<dim3(Ncode), dim3(64), 0, stream>>>(w, wnorm, wh);
    k_mfma<<<dim3(128 * NSPLIT), dim3(256), 0, stream>>>(sh, wh, wnorm,
                                                         pv1, pi1, pv2);
    k_merge<<<dim3(Mtok / 256), dim3(256), 0, stream>>>(pv1, pi1, pv2, fidx, flag,
                                                        list, count);
    k_rescue<<<dim3(RNCH, 64), dim3(256), 0, stream>>>(z_out, w, wnorm, list, count,
                                                       pcv, pci);
    k_gather<<<dim3(Mtok / 4), dim3(256), 0, stream>>>(w, fidx, flag, pcv, pci,
                                                       zq, idxout);
}

// Round 7
// 224.661 us; speedup vs baseline: 7.1219x; 7.1219x over previous
//
#include <hip/hip_runtime.h>
#include <hip/hip_bf16.h>
#include <cstddef>
#include <cstdint>

typedef unsigned short u16;

#define Mtok  16384
#define Ncode 8192
#define Kdim  256
#define NSPLIT 8
#define NPER  (Ncode / NSPLIT)    // 1024 codes per split
#define NT    (NPER / 128)        // 8 column tiles of 128 per block
#define TH_MARGIN 1.0f            // candidate window: ~20 sigma of bf16 err (0.05)
#define RCHUNK 256                // full-rescue: codes per chunk
#define RNCH  (Ncode / RCHUNK)    // 32 chunks

typedef __bf16 bf16x8 __attribute__((ext_vector_type(8)));
typedef float  f32x4  __attribute__((ext_vector_type(4)));

#define LDSP(p) ((__attribute__((address_space(3))) void*)(p))
#define GPTR(p) ((const __attribute__((address_space(1))) void*)(p))

__device__ __forceinline__ u16 f2bf(float x) {
    __hip_bfloat16 h = __float2bfloat16(x);
    return *reinterpret_cast<u16*>(&h);
}

// ---------------------------------------------------------------------------
// Kernel 1: transpose z -> z_out (fp32), plus bf16 s = -2*z.
// Also zeroes the rescue counter (stream-ordered before k_merge).
__global__ __launch_bounds__(256) void k_prep(const float* __restrict__ z,
        float* __restrict__ z_out, u16* __restrict__ sh, int* __restrict__ count) {
    __shared__ float tile[32][33];
    const int b  = blockIdx.z;
    const int c0 = blockIdx.y * 32;
    const int p0 = blockIdx.x * 32;
    const int tx = threadIdx.x;   // 0..31
    const int ty = threadIdx.y;   // 0..7
    if (b == 0 && c0 == 0 && p0 == 0 && tx == 0 && ty == 0) count[0] = 0;
    const float* src = z + ((size_t)b * Kdim + c0) * 1024 + p0;
#pragma unroll
    for (int i = 0; i < 32; i += 8)
        tile[ty + i][tx] = src[(size_t)(ty + i) * 1024 + tx];
    __syncthreads();
#pragma unroll
    for (int i = 0; i < 32; i += 8) {
        const float v = tile[tx][ty + i];
        const size_t m = (size_t)b * 1024 + p0 + ty + i;
        const int    c = c0 + tx;
        z_out[m * Kdim + c] = v;
        sh[m * Kdim + c] = f2bf(-2.0f * v);
    }
}

// ---------------------------------------------------------------------------
// Kernel 2: per-code ||w||^2 plus bf16 wh. One wave per code row.
__global__ __launch_bounds__(64) void k_wsplit(const float* __restrict__ w,
        float* __restrict__ wnorm, u16* __restrict__ wh) {
    const int row  = blockIdx.x;
    const int lane = threadIdx.x;
    const float4 v = ((const float4*)(w + (size_t)row * Kdim))[lane];
    float s = v.x * v.x + v.y * v.y + v.z * v.z + v.w * v.w;
#pragma unroll
    for (int off = 32; off > 0; off >>= 1)
        s += __shfl_down(s, off, 64);
    if (lane == 0) wnorm[row] = s;
    ushort4 ph;
    u16* hp = (u16*)&ph;
    hp[0] = f2bf(v.x); hp[1] = f2bf(v.y); hp[2] = f2bf(v.z); hp[3] = f2bf(v.w);
    *(ushort4*)(wh + (size_t)row * Kdim + lane * 4) = ph;
}

// ---------------------------------------------------------------------------
// Kernel 3 (round-10): single-product R6 skeleton + per-split TOP-3 tracking
// (v1,i1,v2,i2,v3; v3 value-only, for candidate-completeness detection).
// Round rr: vmcnt(2) -> s_barrier -> [ks==0: acc=wn] -> 8x{ds_read + 2 MFMA}
// (setprio) -> lgkmcnt(0) -> s_barrier -> stage(rr+2 -> buf[rr&1]).
__global__ __launch_bounds__(256, 2) void k_mfma(
        const u16* __restrict__ sh, const u16* __restrict__ wh,
        const float* __restrict__ wnorm,
        float* __restrict__ pv1, int* __restrict__ pi1,
        float* __restrict__ pv2, int* __restrict__ pi2,
        float* __restrict__ pv3) {
    __shared__ __align__(16) u16 Bh[2][128 * 32];
    __shared__ __align__(16) float wn_lds[NPER];
    const int tid  = threadIdx.x;
    const int w    = tid >> 6;          // wave 0..3
    const int lane = tid & 63;
    const int l15  = lane & 15;
    const int q    = lane >> 4;         // 0..3
    const int y    = blockIdx.x & 7;    // n-split (XCD pin)
    const int x    = blockIdx.x >> 3;   // m-tile
    const int m0   = x * 128;
    const int n0   = y * NPER;
    const int srow = lane >> 2;         // staging: 16 rows x 4 16B-chunks
    const int sq   = lane & 3;
    const int sqg  = sq ^ ((srow >> 1) & 3);     // pre-swizzled source chunk
    const int qsw  = (q ^ ((l15 >> 1) & 3)) * 8; // swizzled read slot (elems)

    // ---- prologue: A fragments -> registers (direct global, un-swizzled) ---
    bf16x8 ah[8][2];
#pragma unroll
    for (int ks = 0; ks < 8; ++ks)
#pragma unroll
        for (int i = 0; i < 2; ++i) {
            const size_t ra = (size_t)(m0 + w * 32 + i * 16 + l15) * Kdim
                              + ks * 32 + q * 8;
            ah[ks][i] = *(const bf16x8*)(sh + ra);
        }
    // wnorm -> LDS: each lane 16B, wave-uniform LDS base (gload_lds rule)
    __builtin_amdgcn_global_load_lds(GPTR(wnorm + n0 + w * 256 + lane * 4),
                                     LDSP(wn_lds + w * 256), 16, 0, 0);
    // stage B for rounds 0 and 1 (2 loads/wave each)
#pragma unroll
    for (int rr = 0; rr < 2; ++rr) {
        const int kk = rr * 32;
#pragma unroll
        for (int t = 0; t < 2; ++t) {
            const int r  = w * 32 + t * 16 + srow;
            const int lb = (w * 32 + t * 16) * 32;
            const size_t gb = (size_t)(n0 + r) * Kdim + kk + sqg * 8;
            __builtin_amdgcn_global_load_lds(GPTR(wh + gb), LDSP(&Bh[rr][lb]), 16, 0, 0);
        }
    }

    // top-3 state per slot s=i*4+r -> row m0+w*32+i*16+q*4+r
    float v1[8], v2[8], v3[8]; int i1[8], i2[8];
#pragma unroll
    for (int s = 0; s < 8; ++s) {
        v1[s] = 3.0e38f; v2[s] = 3.0e38f; v3[s] = 3.0e38f;
        i1[s] = 0x7fffffff; i2[s] = 0x7fffffff;
    }

    f32x4 acc[2][8];
#pragma unroll 1
    for (int nt = 0; nt < NT; ++nt) {
        const int nb = n0 + nt * 128;
#pragma unroll
        for (int ks = 0; ks < 8; ++ks) {
            const int rr  = nt * 8 + ks;
            const int par = rr & 1;
            // vmcnt ledger: outstanding = stage(rr)[2] + stage(rr+1)[2];
            // round 0 additionally A(16)+wn(1) older; round 63: drain to 0.
            if (rr == NT * 8 - 1) {
                asm volatile("s_waitcnt vmcnt(0)" ::: "memory");
            } else {
                asm volatile("s_waitcnt vmcnt(2)" ::: "memory");
            }
            __builtin_amdgcn_s_barrier();   // all waves' stages for rr visible
            if (ks == 0) {
#pragma unroll
                for (int j = 0; j < 8; ++j) {
                    const float wv = wn_lds[nt * 128 + j * 16 + l15];
#pragma unroll
                    for (int i = 0; i < 2; ++i) {
                        acc[i][j][0] = wv; acc[i][j][1] = wv;
                        acc[i][j][2] = wv; acc[i][j][3] = wv;
                    }
                }
            }
            __builtin_amdgcn_s_setprio(1);
#pragma unroll
            for (int j = 0; j < 8; ++j) {
                const bf16x8 bh_ = *(const bf16x8*)&Bh[par][(j * 16 + l15) * 32 + qsw];
                acc[0][j] = __builtin_amdgcn_mfma_f32_16x16x32_bf16(ah[ks][0], bh_, acc[0][j], 0, 0, 0);
                acc[1][j] = __builtin_amdgcn_mfma_f32_16x16x32_bf16(ah[ks][1], bh_, acc[1][j], 0, 0, 0);
            }
            __builtin_amdgcn_s_setprio(0);
            // all my ds_reads of buf[par] done (stage below can't overtake)
            asm volatile("s_waitcnt lgkmcnt(0)" ::: "memory");
            __builtin_amdgcn_s_barrier();   // all waves done reading buf[par]
            if (rr + 2 < NT * 8) {          // stage round rr+2 into buf[par]
                const int rr2 = rr + 2;
                const int nb2 = n0 + (rr2 >> 3) * 128;
                const int kk2 = (rr2 & 7) * 32;
#pragma unroll
                for (int t = 0; t < 2; ++t) {
                    const int r  = w * 32 + t * 16 + srow;
                    const int lb = (w * 32 + t * 16) * 32;
                    const size_t gb = (size_t)(nb2 + r) * Kdim + kk2 + sqg * 8;
                    __builtin_amdgcn_global_load_lds(GPTR(wh + gb), LDSP(&Bh[par][lb]), 16, 0, 0);
                }
            }
        }
        // top-3 update (idx ascending per lane scan -> strict < = first-min)
#pragma unroll
        for (int i = 0; i < 2; ++i)
#pragma unroll
            for (int r = 0; r < 4; ++r) {
                const int s = i * 4 + r;
#pragma unroll
                for (int j = 0; j < 8; ++j) {
                    const float d   = acc[i][j][r];
                    const int   idx = nb + j * 16 + l15;
                    const bool  b1  = d < v1[s];
                    const bool  b2  = d < v2[s];
                    // v3: if displaces v2, old v2 slides down; else min absorbs d
                    v3[s] = b2 ? v2[s] : fminf(v3[s], d);
                    v2[s] = b1 ? v1[s] : (b2 ? d : v2[s]);
                    i2[s] = b1 ? i1[s] : (b2 ? idx : i2[s]);
                    v1[s] = b1 ? d : v1[s];
                    i1[s] = b1 ? idx : i1[s];
                }
            }
    }
    // butterfly merge of two sorted top-3 sets across the 16 row-lanes
#pragma unroll
    for (int msk = 1; msk < 16; msk <<= 1) {
#pragma unroll
        for (int s = 0; s < 8; ++s) {
            const float b1v = __shfl_xor(v1[s], msk, 64);
            const int   b1i = __shfl_xor(i1[s], msk, 64);
            const float b2v = __shfl_xor(v2[s], msk, 64);
            const int   b2i = __shfl_xor(i2[s], msk, 64);
            const float b3v = __shfl_xor(v3[s], msk, 64);
            const bool keepA = (v1[s] < b1v) || (v1[s] == b1v && i1[s] < b1i);
            const float w1 = keepA ? v1[s] : b1v;  const int wi1 = keepA ? i1[s] : b1i;
            const float l1 = keepA ? b1v : v1[s];  const int li1 = keepA ? b1i : i1[s];
            const float c2 = keepA ? v2[s] : b2v;  const int ci2 = keepA ? i2[s] : b2i;
            const bool t2 = (l1 < c2) || (l1 == c2 && li1 < ci2);
            const float w2 = t2 ? l1 : c2;         const int wi2 = t2 ? li1 : ci2;
            // 3rd smallest of union (values only): min(max(a2,b1),max(a1,b2),min(a3,b3))
            const float w3 = fminf(fminf(fmaxf(v2[s], b1v), fmaxf(v1[s], b2v)),
                                   fminf(v3[s], b3v));
            v1[s] = w1; i1[s] = wi1; v2[s] = w2; i2[s] = wi2; v3[s] = w3;
        }
    }
    if (l15 == 0) {
#pragma unroll
        for (int i = 0; i < 2; ++i)
#pragma unroll
            for (int r = 0; r < 4; ++r) {
                const int s = i * 4 + r;
                const int m = m0 + w * 32 + i * 16 + q * 4 + r;
                pv1[(size_t)y * Mtok + m] = v1[s];
                pi1[(size_t)y * Mtok + m] = i1[s];
                pv2[(size_t)y * Mtok + m] = v2[s];
                pi2[(size_t)y * Mtok + m] = i2[s];
                pv3[(size_t)y * Mtok + m] = v3[s];
            }
    }
}

// ---------------------------------------------------------------------------
// Kernel 4: merge split top-3s -> resolved idx OR candidate list OR full-rescue.
// flag: 0 = resolved (fidx); n>=2 = narrow rescore of n candidates; -1 = full.
// Completeness: code with approx d < gb1+TH is split-rank<=2 (captured) or
// its split's v3 < gb1+TH (detected -> full).  TH > 2*err_max.
__global__ __launch_bounds__(256) void k_merge(
        const float* __restrict__ pv1, const int* __restrict__ pi1,
        const float* __restrict__ pv2, const int* __restrict__ pi2,
        const float* __restrict__ pv3, int* __restrict__ fidx,
        int* __restrict__ flag, int* __restrict__ cands,
        int* __restrict__ list, int* __restrict__ count) {
    const int t = blockIdx.x * 256 + threadIdx.x;
    float a1[NSPLIT], a2[NSPLIT], a3[NSPLIT];
    int   x1[NSPLIT], x2[NSPLIT];
#pragma unroll
    for (int s = 0; s < NSPLIT; ++s) {
        a1[s] = pv1[(size_t)s * Mtok + t];
        x1[s] = pi1[(size_t)s * Mtok + t];
        a2[s] = pv2[(size_t)s * Mtok + t];
        x2[s] = pi2[(size_t)s * Mtok + t];
        a3[s] = pv3[(size_t)s * Mtok + t];
    }
    float gb1 = 3.0e38f; int gi1 = 0x7fffffff;
#pragma unroll
    for (int s = 0; s < NSPLIT; ++s) {
        const bool wn = (a1[s] < gb1) || (a1[s] == gb1 && x1[s] < gi1);
        gb1 = wn ? a1[s] : gb1;
        gi1 = wn ? x1[s] : gi1;
    }
    const float lim = gb1 + TH_MARGIN;
    bool full = false;
#pragma unroll
    for (int s = 0; s < NSPLIT; ++s) full |= (a3[s] < lim);
    int nc = 0;
#pragma unroll
    for (int s = 0; s < NSPLIT; ++s) {
        if (a1[s] < lim) cands[(size_t)t * 16 + nc++] = x1[s];
        if (a2[s] < lim) cands[(size_t)t * 16 + nc++] = x2[s];
    }
    fidx[t] = gi1;
    int f = 0;
    if (full) {
        f = -1;
        const int p = atomicAdd(count, 1);
        list[p] = t;
    } else if (nc >= 2) {
        f = nc;
    }
    flag[t] = f;
}

// ---------------------------------------------------------------------------
// Kernel 5: exact fp32 full rescore (rare safety net), over code chunks.
__global__ __launch_bounds__(256) void k_rescue(
        const float* __restrict__ z_out, const float* __restrict__ w,
        const float* __restrict__ wnorm, const int* __restrict__ list,
        const int* __restrict__ count,
        float* __restrict__ pcv, int* __restrict__ pci) {
    const int bx   = blockIdx.x;       // chunk
    const int tid  = threadIdx.x;
    const int wv   = tid >> 6;
    const int lane = tid & 63;
    __shared__ float rv[4];
    __shared__ int   ri[4];
    const int cnt = count[0];
    for (int it = blockIdx.y; it < cnt; it += gridDim.y) {
        const int t = list[it];
        const float4 zv = *(const float4*)(z_out + (size_t)t * Kdim + lane * 4);
        float bd = 3.0e38f; int bn = 0x7fffffff;
#pragma unroll 4
        for (int i = 0; i < RCHUNK / 4; ++i) {
            const int n = bx * RCHUNK + i * 4 + wv;
            const float4 wr = *(const float4*)(w + (size_t)n * Kdim + lane * 4);
            float s = fmaf(wr.x, zv.x, fmaf(wr.y, zv.y,
                      fmaf(wr.z, zv.z, wr.w * zv.w)));
#pragma unroll
            for (int msk = 1; msk < 64; msk <<= 1)
                s += __shfl_xor(s, msk, 64);
            const float d = wnorm[n] - 2.0f * s;
            if (d < bd) { bd = d; bn = n; }
        }
        if (lane == 0) { rv[wv] = bd; ri[wv] = bn; }
        __syncthreads();
        if (tid == 0) {
            float b = rv[0]; int bi = ri[0];
#pragma unroll
            for (int k = 1; k < 4; ++k)
                if (rv[k] < b || (rv[k] == b && ri[k] < bi)) { b = rv[k]; bi = ri[k]; }
            pcv[(size_t)t * RNCH + bx] = b;
            pci[(size_t)t * RNCH + bx] = bi;
        }
        __syncthreads();
    }
}

// ---------------------------------------------------------------------------
// Kernel 6: gather z_q = weight[idx] + per-token resolution. One wave/token.
// flag==0: fidx. flag==n: exact fp32 rescore of the n candidates (wave
// butterfly dot, all lanes converge). flag==-1: merge RNCH full partials.
__global__ __launch_bounds__(256) void k_gather(
        const float* __restrict__ z_out, const float* __restrict__ w,
        const float* __restrict__ wnorm, const int* __restrict__ fidx,
        const int* __restrict__ flag, const int* __restrict__ cands,
        const float* __restrict__ pcv, const int* __restrict__ pci,
        float* __restrict__ zq, float* __restrict__ idx_out) {
    const int token = blockIdx.x * 4 + (threadIdx.x >> 6);
    const int lane  = threadIdx.x & 63;
    const int f = flag[token];
    int bi = fidx[token];
    if (f == -1) {
        float v = 3.0e38f; int ii = 0x7fffffff;
        if (lane < RNCH) {
            v  = pcv[(size_t)token * RNCH + lane];
            ii = pci[(size_t)token * RNCH + lane];
        }
#pragma unroll
        for (int msk = 1; msk < 64; msk <<= 1) {
            const float ov = __shfl_xor(v, msk, 64);
            const int   oi = __shfl_xor(ii, msk, 64);
            if (ov < v || (ov == v && oi < ii)) { v = ov; ii = oi; }
        }
        bi = ii;
    } else if (f > 0) {
        const float4 zv = *(const float4*)(z_out + (size_t)token * Kdim + lane * 4);
        float bv = 3.0e38f; int bn = 0x7fffffff;
#pragma unroll 1
        for (int c = 0; c < f; ++c) {
            const int n = cands[(size_t)token * 16 + c];
            const float4 wr = *(const float4*)(w + (size_t)n * Kdim + lane * 4);
            float s = fmaf(wr.x, zv.x, fmaf(wr.y, zv.y,
                      fmaf(wr.z, zv.z, wr.w * zv.w)));
#pragma unroll
            for (int msk = 1; msk < 64; msk <<= 1)
                s += __shfl_xor(s, msk, 64);
            const float d = wnorm[n] - 2.0f * s;
            if (d < bv || (d == bv && n < bn)) { bv = d; bn = n; }
        }
        bi = bn;   // uniform: butterfly gives all lanes the full sum
    }
    const float4 u = *(const float4*)(w + (size_t)bi * Kdim + lane * 4);
    *(float4*)(zq + (size_t)token * Kdim + lane * 4) = u;
    if (lane == 0) idx_out[token] = (float)bi;
}

// ---------------------------------------------------------------------------
extern "C" void kernel_launch(void* const* d_in, const int* in_sizes, int n_in,
                              void* d_out, int out_size, void* d_ws, size_t ws_size,
                              hipStream_t stream) {
    const float* z = (const float*)d_in[0];
    const float* w = (const float*)d_in[1];

    float* z_out  = (float*)d_out;                          // [16384, 256]
    float* zq     = z_out + (size_t)Mtok * Kdim;            // [16384, 256]
    float* idxout = zq + (size_t)Mtok * Kdim;               // [16384]

    char* ws = (char*)d_ws;
    u16*   sh    = (u16*)ws;                       ws += (size_t)Mtok * Kdim * 2;
    u16*   wh    = (u16*)ws;                       ws += (size_t)Ncode * Kdim * 2;
    float* wnorm = (float*)ws;                     ws += (size_t)Ncode * 4;
    float* pv1   = (float*)ws;                     ws += (size_t)NSPLIT * Mtok * 4;
    int*   pi1   = (int*)ws;                       ws += (size_t)NSPLIT * Mtok * 4;
    float* pv2   = (float*)ws;                     ws += (size_t)NSPLIT * Mtok * 4;
    int*   pi2   = (int*)ws;                       ws += (size_t)NSPLIT * Mtok * 4;
    float* pv3   = (float*)ws;                     ws += (size_t)NSPLIT * Mtok * 4;
    int*   fidx  = (int*)ws;                       ws += (size_t)Mtok * 4;
    int*   flag  = (int*)ws;                       ws += (size_t)Mtok * 4;
    int*   cands = (int*)ws;                       ws += (size_t)Mtok * 16 * 4;
    int*   list  = (int*)ws;                       ws += (size_t)Mtok * 4;
    int*   count = (int*)ws;                       ws += 256;
    float* pcv   = (float*)ws;                     ws += (size_t)Mtok * RNCH * 4;
    int*   pci   = (int*)ws;                       ws += (size_t)Mtok * RNCH * 4;

    k_prep<<<dim3(1024 / 32, Kdim / 32, 16), dim3(32, 8), 0, stream>>>(z, z_out, sh, count);
    k_wsplit<<<dim3(Ncode), dim3(64), 0, stream>>>(w, wnorm, wh);
    k_mfma<<<dim3(128 * NSPLIT), dim3(256), 0, stream>>>(sh, wh, wnorm,
                                                         pv1, pi1, pv2, pi2, pv3);
    k_merge<<<dim3(Mtok / 256), dim3(256), 0, stream>>>(pv1, pi1, pv2, pi2, pv3,
                                                        fidx, flag, cands, list, count);
    k_rescue<<<dim3(RNCH, 64), dim3(256), 0, stream>>>(z_out, w, wnorm, list, count,
                                                       pcv, pci);
    k_gather<<<dim3(Mtok / 4), dim3(256), 0, stream>>>(z_out, w, wnorm, fidx, flag,
                                                       cands, pcv, pci, zq, idxout);
}